// Round 3
// baseline (383.566 us; speedup 1.0000x reference)
//
#include <hip/hip_runtime.h>

// MeanAggregator: out[b,:] = sum_s (w[b,s] * features[idx[b,s], :]) / sum_s w[b,s]
// B=16384, S=32, D=512, features [100000,512] f32.
// Memory-bound random gather (1.07 GB demand). Round-1: 177us, FETCH 516MB,
// demand BW ~6.0 TB/s. This round: deeper memory pipeline (2x8 float4 double
// buffer, 16 loads in flight per wave) to test latency-bound hypothesis.

#define EMBED_DIM    512
#define NUM_SAMPLE   32
#define VECS_PER_ROW (EMBED_DIM / 4)   // 128 float4 per feature row

__global__ __launch_bounds__(256) void mean_agg_kernel(
    const float* __restrict__ features,
    const float* __restrict__ neigh_weight,
    const int*   __restrict__ neigh_idx,
    float*       __restrict__ out,
    int batch)
{
    const int half = threadIdx.x >> 7;      // which of the 2 rows this block serves
    const int lane = threadIdx.x & 127;     // float4 column within the row
    const int row  = blockIdx.x * 2 + half;

    __shared__ float s_w[2][NUM_SAMPLE];
    __shared__ int   s_idx[2][NUM_SAMPLE];

    if (row < batch && lane < NUM_SAMPLE) {
        s_w[half][lane]   = neigh_weight[row * NUM_SAMPLE + lane];
        s_idx[half][lane] = neigh_idx[row * NUM_SAMPLE + lane];
    }
    __syncthreads();
    if (row >= batch) return;

    // Row sum of weights (broadcast LDS reads, conflict-free).
    float sum = 0.0f;
    #pragma unroll
    for (int s = 0; s < NUM_SAMPLE; ++s) sum += s_w[half][s];
    const float inv = 1.0f / sum;

    const float4* __restrict__ f4 = reinterpret_cast<const float4*>(features);
    float4 acc = make_float4(0.0f, 0.0f, 0.0f, 0.0f);

    // Software-pipelined gather: two 8-deep register buffers; issue group k+1
    // before consuming group k. All indices compile-time (full unroll) so the
    // buffers stay in registers (no scratch).
    float4 b0[8], b1[8];

#define LOAD_GRP(buf, base)                                                   \
    _Pragma("unroll")                                                         \
    for (int j = 0; j < 8; ++j)                                               \
        buf[j] = f4[(size_t)s_idx[half][(base) + j] * VECS_PER_ROW + lane];

#define FMA_GRP(buf, base)                                                    \
    _Pragma("unroll")                                                         \
    for (int j = 0; j < 8; ++j) {                                             \
        const float w = s_w[half][(base) + j];                                \
        acc.x = fmaf(w, buf[j].x, acc.x);                                     \
        acc.y = fmaf(w, buf[j].y, acc.y);                                     \
        acc.z = fmaf(w, buf[j].z, acc.z);                                     \
        acc.w = fmaf(w, buf[j].w, acc.w);                                     \
    }

    LOAD_GRP(b0, 0)      // s =  0.. 7 in flight
    LOAD_GRP(b1, 8)      // s =  8..15 in flight (16 outstanding)
    FMA_GRP (b0, 0)
    LOAD_GRP(b0, 16)     // s = 16..23 in flight
    FMA_GRP (b1, 8)
    LOAD_GRP(b1, 24)     // s = 24..31 in flight
    FMA_GRP (b0, 16)
    FMA_GRP (b1, 24)

#undef LOAD_GRP
#undef FMA_GRP

    acc.x *= inv; acc.y *= inv; acc.z *= inv; acc.w *= inv;
    reinterpret_cast<float4*>(out)[(size_t)row * VECS_PER_ROW + lane] = acc;
}

extern "C" void kernel_launch(void* const* d_in, const int* in_sizes, int n_in,
                              void* d_out, int out_size, void* d_ws, size_t ws_size,
                              hipStream_t stream) {
    const float* features     = (const float*)d_in[0];
    const float* neigh_weight = (const float*)d_in[1];
    const int*   neigh_idx    = (const int*)d_in[2];
    float*       out          = (float*)d_out;

    const int batch = in_sizes[1] / NUM_SAMPLE;          // 16384
    const int grid  = (batch + 1) / 2;                   // 2 rows per 256-thread block

    mean_agg_kernel<<<dim3(grid), dim3(256), 0, stream>>>(
        features, neigh_weight, neigh_idx, out, batch);
}

// Round 5
// 382.327 us; speedup vs baseline: 1.0032x; 1.0032x over previous
//
#include <hip/hip_runtime.h>

// MeanAggregator: out[b,:] = sum_s (w[b,s] * features[idx[b,s], :]) / sum_s w[b,s]
// B=16384, S=32, D=512, features [100000,512] f32.
// R1: 177us, FETCH 516MB, demand BW 6.25 TB/s (~= copy ceiling).
// R3: 16-deep pipeline neutral -> not wave-MLP-bound.
// R5: non-temporal output stores (via clang ext_vector_type — HIP float4 is a
// class and rejected by the builtin). Write-once 33.5MB stream should stop
// churning L2 (4.2MB/XCD) / polluting L3, shrinking the 516MB HBM fetch.

#define EMBED_DIM    512
#define NUM_SAMPLE   32
#define VECS_PER_ROW (EMBED_DIM / 4)   // 128 float4 per feature row

typedef float f32x4 __attribute__((ext_vector_type(4)));

__global__ __launch_bounds__(256) void mean_agg_kernel(
    const float* __restrict__ features,
    const float* __restrict__ neigh_weight,
    const int*   __restrict__ neigh_idx,
    float*       __restrict__ out,
    int batch)
{
    const int half = threadIdx.x >> 7;      // which of the 2 rows this block serves
    const int lane = threadIdx.x & 127;     // float4 column within the row
    const int row  = blockIdx.x * 2 + half;

    __shared__ float s_w[2][NUM_SAMPLE];
    __shared__ int   s_idx[2][NUM_SAMPLE];

    if (row < batch && lane < NUM_SAMPLE) {
        s_w[half][lane]   = neigh_weight[row * NUM_SAMPLE + lane];
        s_idx[half][lane] = neigh_idx[row * NUM_SAMPLE + lane];
    }
    __syncthreads();
    if (row >= batch) return;

    // Row sum of weights (broadcast LDS reads, conflict-free).
    float sum = 0.0f;
    #pragma unroll
    for (int s = 0; s < NUM_SAMPLE; ++s) sum += s_w[half][s];
    const float inv = 1.0f / sum;

    const f32x4* __restrict__ f4 = reinterpret_cast<const f32x4*>(features);
    f32x4 acc;
    acc.x = 0.0f; acc.y = 0.0f; acc.z = 0.0f; acc.w = 0.0f;

    // Gather-accumulate. unroll 8 -> 8 independent global loads in flight/thread
    // (R3 showed deeper pipelining is neutral; keep the simple form).
    #pragma unroll 8
    for (int s = 0; s < NUM_SAMPLE; ++s) {
        const float  w   = s_w[half][s];
        const size_t off = (size_t)s_idx[half][s] * VECS_PER_ROW + lane;
        const f32x4  v   = f4[off];
        acc.x = fmaf(w, v.x, acc.x);
        acc.y = fmaf(w, v.y, acc.y);
        acc.z = fmaf(w, v.z, acc.z);
        acc.w = fmaf(w, v.w, acc.w);
    }

    acc.x *= inv; acc.y *= inv; acc.z *= inv; acc.w *= inv;

    // Non-temporal store: output is write-once, never re-read. Keep it out of
    // L2/L3 so it doesn't evict feature rows.
    f32x4* dst = &reinterpret_cast<f32x4*>(out)[(size_t)row * VECS_PER_ROW + lane];
    __builtin_nontemporal_store(acc, dst);
}

extern "C" void kernel_launch(void* const* d_in, const int* in_sizes, int n_in,
                              void* d_out, int out_size, void* d_ws, size_t ws_size,
                              hipStream_t stream) {
    const float* features     = (const float*)d_in[0];
    const float* neigh_weight = (const float*)d_in[1];
    const int*   neigh_idx    = (const int*)d_in[2];
    float*       out          = (float*)d_out;

    const int batch = in_sizes[1] / NUM_SAMPLE;          // 16384
    const int grid  = (batch + 1) / 2;                   // 2 rows per 256-thread block

    mean_agg_kernel<<<dim3(grid), dim3(256), 0, stream>>>(
        features, neigh_weight, neigh_idx, out, batch);
}